// Round 4
// baseline (2077.977 us; speedup 1.0000x reference)
//
#include <hip/hip_runtime.h>
#include <math.h>

#define HID 64
#define TST 2048
#define CH 16              // timesteps per chunk
#define NCH (TST / CH)     // 128 chunks
#define EPSN 1e-5f

typedef float v2f __attribute__((ext_vector_type(2)));

__device__ __forceinline__ float bcast(float v, int k) {
    return __int_as_float(__builtin_amdgcn_readlane(__float_as_int(v), k));
}

// ---------------------------------------------------------------------------
// Single fused kernel. grid = B (256), 256 threads (4 waves), 1 block/CU.
// Phase pipeline (one __syncthreads per phase):
//   wave 3 : prefetch ce chunk p+1 -> cebuf ; LN(h@w2+b2) epilogue chunk p-3
//   waves 1-2: x = GELU(LN(ce@w1+b1)) for chunk p (8 rows each) -> xbuf ;
//              gi = W_ih.x + b_ih for chunk p-1 from xbuf (pk-FMA) -> gibuf
//   wave 0 : serial GRU scan of chunk p-2. h lives in registers; lane k's h
//            is broadcast via v_readlane (no LDS on the critical path).
//            W_hh rows in 192 VGPRs. h written to hist (never read back).
// ---------------------------------------------------------------------------
__global__ __launch_bounds__(256, 1)
__attribute__((amdgpu_waves_per_eu(1, 1)))
void k_fused(const float* __restrict__ ce,
             const float* __restrict__ w1, const float* __restrict__ b1,
             const float* __restrict__ g1, const float* __restrict__ be1,
             const float* __restrict__ W_ih, const float* __restrict__ b_ih,
             const float* __restrict__ W_hh, const float* __restrict__ b_hh,
             const float* __restrict__ w2, const float* __restrict__ b2,
             const float* __restrict__ g2, const float* __restrict__ be2,
             float* __restrict__ out) {
    __shared__ float2 cebuf[2][CH * 3];                   // 768 B  ce rows
    __shared__ __align__(16) float xbuf[2][CH][HID];      // 8 KB   x chunks
    __shared__ __align__(16) float gibuf[2][3][CH][HID];  // 24 KB  gi preacts
    __shared__ __align__(16) float hist[2][CH][HID];      // 8 KB   h history

    const int tid = threadIdx.x;
    const int lane = tid & 63;
    const int wv = tid >> 6;
    const float* ceb = ce + (size_t)blockIdx.x * TST * 6;
    float* ob = out + (size_t)blockIdx.x * TST * HID;

    // ---- per-role register state ----
    float whr[HID], whz[HID], whn[HID];   // wave 0: W_hh rows (192 VGPRs)
    float bhr = 0.f, bhz = 0.f, bhn = 0.f;
    v2f wiA[32], wiB[32];                 // waves 1-2: W_ih rows
    float biA = 0.f, biB = 0.f;
    float w1c[6], b1r = 0.f, g1r = 0.f, be1r = 0.f;  // waves 1-2: inproj col
    v2f w2v[32];                          // wave 3: w2 column
    float b2r = 0.f, g2r = 0.f, be2r = 0.f;

    if (wv == 0) {
#pragma unroll
        for (int k = 0; k < HID; ++k) {
            whr[k] = W_hh[(size_t)lane * HID + k];
            whz[k] = W_hh[(size_t)(64 + lane) * HID + k];
            whn[k] = W_hh[(size_t)(128 + lane) * HID + k];
        }
        bhr = b_hh[lane]; bhz = b_hh[64 + lane]; bhn = b_hh[128 + lane];
    } else if (wv == 1 || wv == 2) {
        const int rA = (wv == 1) ? lane : (128 + lane);        // r-gate / n-gate
        const v2f* pA = (const v2f*)(W_ih + (size_t)rA * HID);
#pragma unroll
        for (int k = 0; k < 32; ++k) wiA[k] = pA[k];
        biA = b_ih[rA];
        if (wv == 1) {
            const v2f* pB = (const v2f*)(W_ih + (size_t)(64 + lane) * HID);
#pragma unroll
            for (int k = 0; k < 32; ++k) wiB[k] = pB[k];
            biB = b_ih[64 + lane];
        }
#pragma unroll
        for (int i = 0; i < 6; ++i) w1c[i] = w1[i * HID + lane];
        b1r = b1[lane]; g1r = g1[lane]; be1r = be1[lane];
    } else {
#pragma unroll
        for (int k = 0; k < 32; ++k) {
            w2v[k].x = w2[(size_t)(2 * k) * HID + lane];
            w2v[k].y = w2[(size_t)(2 * k + 1) * HID + lane];
        }
        b2r = b2[lane]; g2r = g2[lane]; be2r = be2[lane];
    }

    // ---- prologue: ce chunk 0 into cebuf[0] ----
    if (tid < 48) cebuf[0][tid] = ((const float2*)ceb)[tid];
    float h_reg = 0.0f;
    __syncthreads();

    for (int p = 0; p <= NCH + 2; ++p) {
        if (wv == 0) {
            // ---------------- GRU scan, chunk p-2 ----------------
            if (p >= 2 && p <= NCH + 1) {
                const int c = p - 2;
                const float* gp = &gibuf[c & 1][0][0][0];
                float* hp = &hist[c & 1][0][0];
                for (int t = 0; t < CH; ++t) {
                    // gi reads: needed only at end of dot -> latency hidden
                    const float gr = gp[0 * CH * HID + t * HID + lane];
                    const float gz = gp[1 * CH * HID + t * HID + lane];
                    const float gn = gp[2 * CH * HID + t * HID + lane];
                    float ar = 0.f, az = 0.f, an = 0.f;
#pragma unroll
                    for (int k = 0; k < HID; ++k) {
                        const float hk = bcast(h_reg, k);
                        ar = fmaf(whr[k], hk, ar);
                        az = fmaf(whz[k], hk, az);
                        an = fmaf(whn[k], hk, an);
                    }
                    const float r = 1.0f / (1.0f + __expf(-(gr + ar + bhr)));
                    const float z = 1.0f / (1.0f + __expf(-(gz + az + bhz)));
                    const float pre = gn + r * (an + bhn);
                    const float e2 = __expf(2.0f * pre);
                    const float n = 1.0f - 2.0f / (e2 + 1.0f);
                    h_reg = (1.0f - z) * n + z * h_reg;
                    hp[t * HID + lane] = h_reg;
                }
            }
        } else if (wv == 1 || wv == 2) {
            // ---------------- x = GELU(LN(ce@w1+b1)), chunk p ----------------
            if (p < NCH) {
                const float2* cb = cebuf[p & 1];
                const int base = (wv - 1) * 8;
                float acc[8];
#pragma unroll
                for (int i = 0; i < 8; ++i) {
                    const int row = base + i;
                    const float2 a = cb[row * 3 + 0];
                    const float2 bb = cb[row * 3 + 1];
                    const float2 cc = cb[row * 3 + 2];
                    acc[i] = b1r + a.x * w1c[0] + a.y * w1c[1] + bb.x * w1c[2] +
                             bb.y * w1c[3] + cc.x * w1c[4] + cc.y * w1c[5];
                }
                float sv[8], qv[8];
#pragma unroll
                for (int i = 0; i < 8; ++i) { sv[i] = acc[i]; qv[i] = acc[i] * acc[i]; }
#pragma unroll
                for (int m = 32; m >= 1; m >>= 1) {
#pragma unroll
                    for (int i = 0; i < 8; ++i) sv[i] += __shfl_xor(sv[i], m, 64);
#pragma unroll
                    for (int i = 0; i < 8; ++i) qv[i] += __shfl_xor(qv[i], m, 64);
                }
#pragma unroll
                for (int i = 0; i < 8; ++i) {
                    const float mean = sv[i] * (1.0f / 64.0f);
                    const float var = qv[i] * (1.0f / 64.0f) - mean * mean;
                    const float xn = (acc[i] - mean) * rsqrtf(var + EPSN) * g1r + be1r;
                    xbuf[p & 1][base + i][lane] =
                        0.5f * xn * (1.0f + erff(xn * 0.70710678118654752440f));
                }
            }
            // ---------------- gi = W_ih.x + b_ih, chunk p-1 ----------------
            if (p >= 1 && p <= NCH) {
                const int c = p - 1;
                for (int t = 0; t < CH; ++t) {
                    const v2f* xv = (const v2f*)xbuf[c & 1][t];
                    if (wv == 1) {
                        v2f aR = {0.f, 0.f}, aZ = {0.f, 0.f};
#pragma unroll
                        for (int k = 0; k < 32; ++k) {
                            const v2f xx = xv[k];
                            aR += wiA[k] * xx;
                            aZ += wiB[k] * xx;
                        }
                        gibuf[c & 1][0][t][lane] = aR.x + aR.y + biA;
                        gibuf[c & 1][1][t][lane] = aZ.x + aZ.y + biB;
                    } else {
                        v2f aN = {0.f, 0.f};
#pragma unroll
                        for (int k = 0; k < 32; ++k) aN += wiA[k] * xv[k];
                        gibuf[c & 1][2][t][lane] = aN.x + aN.y + biA;
                    }
                }
            }
        } else {
            // ---------------- wave 3: ce prefetch + epilogue ----------------
            if (p + 1 < NCH && lane < 48)
                cebuf[(p + 1) & 1][lane] =
                    ((const float2*)(ceb + (size_t)(p + 1) * CH * 6))[lane];
            if (p >= 3) {
                const int c = p - 3;
                const float* hp = &hist[c & 1][0][0];
                float yv[CH];
#pragma unroll
                for (int t = 0; t < CH; ++t) {
                    const v2f* hr = (const v2f*)(hp + t * HID);
                    v2f a2 = {0.f, 0.f};
#pragma unroll
                    for (int k = 0; k < 32; ++k) a2 += w2v[k] * hr[k];
                    yv[t] = b2r + a2.x + a2.y;
                }
                float sv[CH], qv[CH];
#pragma unroll
                for (int t = 0; t < CH; ++t) { sv[t] = yv[t]; qv[t] = yv[t] * yv[t]; }
#pragma unroll
                for (int m = 32; m >= 1; m >>= 1) {
#pragma unroll
                    for (int t = 0; t < CH; ++t) sv[t] += __shfl_xor(sv[t], m, 64);
#pragma unroll
                    for (int t = 0; t < CH; ++t) qv[t] += __shfl_xor(qv[t], m, 64);
                }
#pragma unroll
                for (int t = 0; t < CH; ++t) {
                    const float mean = sv[t] * (1.0f / 64.0f);
                    const float var = qv[t] * (1.0f / 64.0f) - mean * mean;
                    const float dd = yv[t] - mean;
                    ob[(size_t)(c * CH + t) * HID + lane] =
                        dd * rsqrtf(var + EPSN) * g2r + be2r;
                }
            }
        }
        __syncthreads();
    }
}

extern "C" void kernel_launch(void* const* d_in, const int* in_sizes, int n_in,
                              void* d_out, int out_size, void* d_ws, size_t ws_size,
                              hipStream_t stream) {
    const float* ce  = (const float*)d_in[0];
    const float* w1  = (const float*)d_in[1];
    const float* b1  = (const float*)d_in[2];
    const float* g1  = (const float*)d_in[3];
    const float* be1 = (const float*)d_in[4];
    const float* Wih = (const float*)d_in[5];
    const float* bih = (const float*)d_in[6];
    const float* Whh = (const float*)d_in[7];
    const float* bhh = (const float*)d_in[8];
    const float* w2  = (const float*)d_in[9];
    const float* b2  = (const float*)d_in[10];
    const float* g2  = (const float*)d_in[11];
    const float* be2 = (const float*)d_in[12];
    float* out = (float*)d_out;

    const int B = (in_sizes[0] / 6) / TST;   // 256

    k_fused<<<B, 256, 0, stream>>>(ce, w1, b1, g1, be1, Wih, bih, Whh, bhh,
                                   w2, b2, g2, be2, out);
}